// Round 1
// baseline (1472.512 us; speedup 1.0000x reference)
//
#include <hip/hip_runtime.h>
#include <cstdint>

#define N_NODES 100000
#define N_EDGES 1600000

// ---------------- K1: xw = x @ W0  [100000,512] x [512,32] ----------------
// BM=128 rows, BN=32 (full), BK=32. 256 threads: 32 rowgroups x 8 colgroups,
// each thread 4 rows x 4 cols. LDS x-tile stored transposed [k][row] with
// row-stride 132 (pad) so staging stores are ~conflict-free and inner reads
// are b128.
__global__ __launch_bounds__(256) void k_gemm_xw(const float* __restrict__ x,
                                                 const float* __restrict__ W,
                                                 float* __restrict__ xw) {
  __shared__ float xs[32][132];
  __shared__ float ws[32][32];
  const int t = threadIdx.x;
  const int rg = t & 31, cg = t >> 5;
  const int r0 = rg * 4, c0 = cg * 4;
  const int brow = blockIdx.x * 128;
  float acc[4][4] = {{0.f}};
  for (int k0 = 0; k0 < 512; k0 += 32) {
#pragma unroll
    for (int i = 0; i < 4; ++i) {
      int f = t + i * 256;           // 0..1023
      int r = f >> 3;                // 0..127
      int kq = (f & 7) << 2;         // 0,4,..,28
      int gr = brow + r;
      float4 v = make_float4(0.f, 0.f, 0.f, 0.f);
      if (gr < N_NODES) v = *(const float4*)(x + (size_t)gr * 512 + k0 + kq);
      xs[kq + 0][r] = v.x; xs[kq + 1][r] = v.y;
      xs[kq + 2][r] = v.z; xs[kq + 3][r] = v.w;
    }
    {
      int k = t >> 3, cq = (t & 7) << 2;
      *(float4*)&ws[k][cq] = *(const float4*)(W + (size_t)(k0 + k) * 32 + cq);
    }
    __syncthreads();
#pragma unroll
    for (int k = 0; k < 32; ++k) {
      float4 a = *(const float4*)&xs[k][r0];
      float4 b = *(const float4*)&ws[k][c0];
      float av[4] = {a.x, a.y, a.z, a.w};
      float bv[4] = {b.x, b.y, b.z, b.w};
#pragma unroll
      for (int i = 0; i < 4; ++i)
#pragma unroll
        for (int j = 0; j < 4; ++j) acc[i][j] += av[i] * bv[j];
    }
    __syncthreads();
  }
#pragma unroll
  for (int i = 0; i < 4; ++i) {
    int gr = brow + r0 + i;
    if (gr < N_NODES) {
      *(float4*)(xw + (size_t)gr * 32 + c0) =
          make_float4(acc[i][0], acc[i][1], acc[i][2], acc[i][3]);
    }
  }
}

// ---------------- small helpers ----------------
__global__ void k_zero(float* __restrict__ a, float* __restrict__ b, int n) {
  int i = blockIdx.x * 256 + threadIdx.x;
  if (i < n) { a[i] = 0.f; b[i] = 0.f; }
}

__global__ void k_deg1(const int* __restrict__ col, float* __restrict__ deg, int E) {
  int e = blockIdx.x * 256 + threadIdx.x;
  if (e < E) atomicAdd(&deg[col[e]], 1.0f);
}

// deg -> rsqrt(deg + 1) in place (the +1 is the self-loop weight; always > 0)
__global__ void k_dinv(float* __restrict__ d, int n) {
  int i = blockIdx.x * 256 + threadIdx.x;
  if (i < n) d[i] = rsqrtf(d[i] + 1.0f);
}

// h[i][:] = xw[i][:] * dinv1[i]^2 + b0  (self-loop + bias init)
__global__ void k_hinit(const float* __restrict__ xw, const float* __restrict__ dinv,
                        const float* __restrict__ b0, float* __restrict__ h) {
  int tid = blockIdx.x * 256 + threadIdx.x;  // N*8 threads (float4 each)
  if (tid >= N_NODES * 8) return;
  int i = tid >> 3, jq = (tid & 7) << 2;
  float s = dinv[i]; s *= s;
  float4 v = *(const float4*)(xw + (size_t)i * 32 + jq);
  float4 b = *(const float4*)(b0 + jq);
  *(float4*)(h + (size_t)i * 32 + jq) =
      make_float4(v.x * s + b.x, v.y * s + b.y, v.z * s + b.z, v.w * s + b.w);
}

// per-edge scatter for conv1: 8 threads/edge, float4 each -> 4 atomics
__global__ void k_conv1(const int* __restrict__ row, const int* __restrict__ col,
                        const float* __restrict__ xw, const float* __restrict__ dinv,
                        float* __restrict__ h) {
  long long tid = (long long)blockIdx.x * 256 + threadIdx.x;  // E*8
  if (tid >= (long long)N_EDGES * 8) return;
  int e = (int)(tid >> 3), jq = ((int)tid & 7) << 2;
  int r = row[e], c = col[e];
  float coef = dinv[r] * dinv[c];
  float4 v = *(const float4*)(xw + (size_t)r * 32 + jq);
  float* dst = h + (size_t)c * 32 + jq;
  atomicAdd(dst + 0, v.x * coef);
  atomicAdd(dst + 1, v.y * coef);
  atomicAdd(dst + 2, v.z * coef);
  atomicAdd(dst + 3, v.w * coef);
}

// fold attention MLP into two per-node 32-vectors + constants:
// u[0:32]  = Wnb @ Watt[0:8]      u[64] = bnb.Watt[0:8] + batt
// u[32:64] = Wself @ Watt[8:16]   u[65] = bself.Watt[8:16]
__global__ void k_prep_u(const float* __restrict__ Wnb, const float* __restrict__ bnb,
                         const float* __restrict__ Wself, const float* __restrict__ bself,
                         const float* __restrict__ Watt, const float* __restrict__ batt,
                         float* __restrict__ u) {
  int t = threadIdx.x;  // 64 threads
  if (t < 32) {
    float a = 0.f;
    for (int j = 0; j < 8; ++j) a += Wnb[t * 8 + j] * Watt[j];
    u[t] = a;
  } else {
    int k = t - 32;
    float a = 0.f;
    for (int j = 0; j < 8; ++j) a += Wself[k * 8 + j] * Watt[8 + j];
    u[32 + k] = a;
  }
  if (t == 0) {
    float a = batt[0];
    for (int j = 0; j < 8; ++j) a += bnb[j] * Watt[j];
    u[64] = a;
  }
  if (t == 1) {
    float a = 0.f;
    for (int j = 0; j < 8; ++j) a += bself[j] * Watt[8 + j];
    u[65] = a;
  }
}

// per-node: s1, s2 scalars + hw = h @ W1 (no bias)
__global__ __launch_bounds__(256) void k_node(const float* __restrict__ h,
                                              const float* __restrict__ u,
                                              const float* __restrict__ W1,
                                              float* __restrict__ s1, float* __restrict__ s2,
                                              float* __restrict__ hw) {
  __shared__ float w1s[256];
  __shared__ float us[66];
  int t = threadIdx.x;
  w1s[t] = W1[t];
  if (t < 66) us[t] = u[t];
  __syncthreads();
  int i = blockIdx.x * 256 + t;
  if (i >= N_NODES) return;
  float hv[32];
#pragma unroll
  for (int q = 0; q < 8; ++q)
    *(float4*)&hv[q * 4] = *(const float4*)(h + (size_t)i * 32 + q * 4);
  float a1 = us[64], a2 = us[65];
#pragma unroll
  for (int k = 0; k < 32; ++k) { a1 += hv[k] * us[k]; a2 += hv[k] * us[32 + k]; }
  s1[i] = a1; s2[i] = a2;
  float o[8] = {0.f, 0.f, 0.f, 0.f, 0.f, 0.f, 0.f, 0.f};
#pragma unroll
  for (int k = 0; k < 32; ++k) {
    float hk = hv[k];
#pragma unroll
    for (int j = 0; j < 8; ++j) o[j] += hk * w1s[k * 8 + j];
  }
  *(float4*)(hw + (size_t)i * 8) = make_float4(o[0], o[1], o[2], o[3]);
  *(float4*)(hw + (size_t)i * 8 + 4) = make_float4(o[4], o[5], o[6], o[7]);
}

// per-edge: weight = relu(s1[r]+s2[c]); mw = min(1.01*sigmoid(w),1)*w; deg2 += mw
__global__ void k_ew(const int* __restrict__ row, const int* __restrict__ col,
                     const float* __restrict__ s1, const float* __restrict__ s2,
                     float* __restrict__ mw, float* __restrict__ deg2) {
  int e = blockIdx.x * 256 + threadIdx.x;
  if (e >= N_EDGES) return;
  float w = s1[row[e]] + s2[col[e]];
  w = fmaxf(w, 0.0f);
  float m = fminf(1.01f / (1.0f + __expf(-w)), 1.0f);  // w>=0 so lower clip inactive
  float v = m * w;
  mw[e] = v;
  atomicAdd(&deg2[col[e]], v);
}

// out[i][:] = hw[i][:] * dinv2[i]^2 + b1  (self-loop + bias init)
__global__ void k_oinit(const float* __restrict__ hw, const float* __restrict__ dinv2,
                        const float* __restrict__ b1, float* __restrict__ out) {
  int tid = blockIdx.x * 256 + threadIdx.x;  // N*2 threads
  if (tid >= N_NODES * 2) return;
  int i = tid >> 1, jq = (tid & 1) << 2;
  float s = dinv2[i]; s *= s;
  float4 v = *(const float4*)(hw + (size_t)i * 8 + jq);
  float4 b = *(const float4*)(b1 + jq);
  *(float4*)(out + (size_t)i * 8 + jq) =
      make_float4(v.x * s + b.x, v.y * s + b.y, v.z * s + b.z, v.w * s + b.w);
}

// per-edge scatter for conv2: 2 threads/edge, float4 each
__global__ void k_conv2(const int* __restrict__ row, const int* __restrict__ col,
                        const float* __restrict__ hw, const float* __restrict__ dinv2,
                        const float* __restrict__ mw, float* __restrict__ out) {
  long long tid = (long long)blockIdx.x * 256 + threadIdx.x;  // E*2
  if (tid >= (long long)N_EDGES * 2) return;
  int e = (int)(tid >> 1), jq = ((int)tid & 1) << 2;
  int r = row[e], c = col[e];
  float coef = dinv2[r] * mw[e] * dinv2[c];
  float4 v = *(const float4*)(hw + (size_t)r * 8 + jq);
  float* dst = out + (size_t)c * 8 + jq;
  atomicAdd(dst + 0, v.x * coef);
  atomicAdd(dst + 1, v.y * coef);
  atomicAdd(dst + 2, v.z * coef);
  atomicAdd(dst + 3, v.w * coef);
}

extern "C" void kernel_launch(void* const* d_in, const int* in_sizes, int n_in,
                              void* d_out, int out_size, void* d_ws, size_t ws_size,
                              hipStream_t stream) {
  const float* x     = (const float*)d_in[0];
  const int*   eidx  = (const int*)d_in[1];
  const int*   row   = eidx;             // edge_idx[0]
  const int*   col   = eidx + N_EDGES;   // edge_idx[1]
  const float* W0    = (const float*)d_in[2];
  const float* b0    = (const float*)d_in[3];
  const float* W1    = (const float*)d_in[4];
  const float* b1    = (const float*)d_in[5];
  const float* Wnb   = (const float*)d_in[6];
  const float* bnb   = (const float*)d_in[7];
  const float* Wself = (const float*)d_in[8];
  const float* bself = (const float*)d_in[9];
  const float* Watt  = (const float*)d_in[10];
  const float* batt  = (const float*)d_in[11];
  float* wsf = (float*)d_ws;

  // workspace layout (floats): total 9,200,066 (~36.8 MB)
  float* xw   = wsf + 0;        // N*32
  float* h    = wsf + 3200000;  // N*32
  float* hw   = wsf + 6400000;  // N*8
  float* mw   = wsf + 7200000;  // E
  float* deg1 = wsf + 8800000;  // N (becomes dinv1)
  float* deg2 = wsf + 8900000;  // N (becomes dinv2)
  float* s1   = wsf + 9000000;  // N
  float* s2   = wsf + 9100000;  // N
  float* u    = wsf + 9200000;  // 66

  float* out = (float*)d_out;

  k_zero<<<(N_NODES + 255) / 256, 256, 0, stream>>>(deg1, deg2, N_NODES);
  k_gemm_xw<<<(N_NODES + 127) / 128, 256, 0, stream>>>(x, W0, xw);
  k_deg1<<<(N_EDGES + 255) / 256, 256, 0, stream>>>(col, deg1, N_EDGES);
  k_dinv<<<(N_NODES + 255) / 256, 256, 0, stream>>>(deg1, N_NODES);
  k_hinit<<<(N_NODES * 8 + 255) / 256, 256, 0, stream>>>(xw, deg1, b0, h);
  k_conv1<<<(int)(((long long)N_EDGES * 8 + 255) / 256), 256, 0, stream>>>(row, col, xw, deg1, h);
  k_prep_u<<<1, 64, 0, stream>>>(Wnb, bnb, Wself, bself, Watt, batt, u);
  k_node<<<(N_NODES + 255) / 256, 256, 0, stream>>>(h, u, W1, s1, s2, hw);
  k_ew<<<(N_EDGES + 255) / 256, 256, 0, stream>>>(row, col, s1, s2, mw, deg2);
  k_dinv<<<(N_NODES + 255) / 256, 256, 0, stream>>>(deg2, N_NODES);
  k_oinit<<<(N_NODES * 2 + 255) / 256, 256, 0, stream>>>(hw, deg2, b1, out);
  k_conv2<<<(int)(((long long)N_EDGES * 2 + 255) / 256), 256, 0, stream>>>(row, col, hw, deg2, mw, out);
}

// Round 2
// 623.089 us; speedup vs baseline: 2.3632x; 2.3632x over previous
//
#include <hip/hip_runtime.h>
#include <cstdint>

#define N_NODES 100000
#define N_EDGES 1600000
#define SCAN_NB 391  // ceil(N_NODES/256)

// ---------------- K1: xw = x @ W0  [100000,512] x [512,32] ----------------
__global__ __launch_bounds__(256) void k_gemm_xw(const float* __restrict__ x,
                                                 const float* __restrict__ W,
                                                 float* __restrict__ xw) {
  __shared__ float xs[32][132];
  __shared__ float ws[32][32];
  const int t = threadIdx.x;
  const int rg = t & 31, cg = t >> 5;
  const int r0 = rg * 4, c0 = cg * 4;
  const int brow = blockIdx.x * 128;
  float acc[4][4] = {{0.f}};
  for (int k0 = 0; k0 < 512; k0 += 32) {
#pragma unroll
    for (int i = 0; i < 4; ++i) {
      int f = t + i * 256;
      int r = f >> 3;
      int kq = (f & 7) << 2;
      int gr = brow + r;
      float4 v = make_float4(0.f, 0.f, 0.f, 0.f);
      if (gr < N_NODES) v = *(const float4*)(x + (size_t)gr * 512 + k0 + kq);
      xs[kq + 0][r] = v.x; xs[kq + 1][r] = v.y;
      xs[kq + 2][r] = v.z; xs[kq + 3][r] = v.w;
    }
    {
      int k = t >> 3, cq = (t & 7) << 2;
      *(float4*)&ws[k][cq] = *(const float4*)(W + (size_t)(k0 + k) * 32 + cq);
    }
    __syncthreads();
#pragma unroll
    for (int k = 0; k < 32; ++k) {
      float4 a = *(const float4*)&xs[k][r0];
      float4 b = *(const float4*)&ws[k][c0];
      float av[4] = {a.x, a.y, a.z, a.w};
      float bv[4] = {b.x, b.y, b.z, b.w};
#pragma unroll
      for (int i = 0; i < 4; ++i)
#pragma unroll
        for (int j = 0; j < 4; ++j) acc[i][j] += av[i] * bv[j];
    }
    __syncthreads();
  }
#pragma unroll
  for (int i = 0; i < 4; ++i) {
    int gr = brow + r0 + i;
    if (gr < N_NODES) {
      *(float4*)(xw + (size_t)gr * 32 + c0) =
          make_float4(acc[i][0], acc[i][1], acc[i][2], acc[i][3]);
    }
  }
}

// ---------------- CSR build ----------------
__global__ void k_zero_cnt(int* __restrict__ cnt, int n) {
  int i = blockIdx.x * 256 + threadIdx.x;
  if (i < n) cnt[i] = 0;
}

__global__ void k_count(const int* __restrict__ col, int* __restrict__ cnt, int E) {
  int e = blockIdx.x * 256 + threadIdx.x;
  if (e < E) atomicAdd(&cnt[col[e]], 1);
}

// per-block exclusive scan (256 wide) + block sums
__global__ __launch_bounds__(256) void k_scan1(const int* __restrict__ cnt,
                                               int* __restrict__ off,
                                               int* __restrict__ bsum) {
  __shared__ int s[256];
  int t = threadIdx.x;
  int i = blockIdx.x * 256 + t;
  int v = (i < N_NODES) ? cnt[i] : 0;
  s[t] = v;
  __syncthreads();
  for (int d = 1; d < 256; d <<= 1) {
    int a = (t >= d) ? s[t - d] : 0;
    __syncthreads();
    s[t] += a;
    __syncthreads();
  }
  if (i < N_NODES) off[i] = s[t] - v;           // exclusive within block
  if (t == 255) bsum[blockIdx.x] = s[255];      // block total
}

// single-block exclusive scan of the 391 block sums
__global__ __launch_bounds__(512) void k_scan2(const int* __restrict__ bsum,
                                               int* __restrict__ bpre) {
  __shared__ int s[512];
  int t = threadIdx.x;
  int v = (t < SCAN_NB) ? bsum[t] : 0;
  s[t] = v;
  __syncthreads();
  for (int d = 1; d < 512; d <<= 1) {
    int a = (t >= d) ? s[t - d] : 0;
    __syncthreads();
    s[t] += a;
    __syncthreads();
  }
  if (t < SCAN_NB) bpre[t] = s[t] - v;
}

// finalize offsets, init cursors, dinv1 = rsqrt(deg+1)
__global__ void k_scan3(const int* __restrict__ cnt, const int* __restrict__ bpre,
                        int* __restrict__ off, int* __restrict__ cursor,
                        float* __restrict__ dinv1) {
  int i = blockIdx.x * 256 + threadIdx.x;
  if (i >= N_NODES) return;
  int o = off[i] + bpre[i >> 8];
  off[i] = o;
  cursor[i] = o;
  dinv1[i] = rsqrtf((float)cnt[i] + 1.0f);
  if (i == 0) off[N_NODES] = N_EDGES;
}

__global__ void k_scatter(const int* __restrict__ row, const int* __restrict__ col,
                          int* __restrict__ cursor, int* __restrict__ ssrc) {
  int e = blockIdx.x * 256 + threadIdx.x;
  if (e >= N_EDGES) return;
  int c = col[e];
  int p = atomicAdd(&cursor[c], 1);
  ssrc[p] = row[e];
}

// ---------------- conv1 ----------------
// h[i][:] = xw[i][:] * dinv1[i]^2 + b0   (self-loop + bias)
__global__ void k_hinit(const float* __restrict__ xw, const float* __restrict__ dinv,
                        const float* __restrict__ b0, float* __restrict__ h) {
  int tid = blockIdx.x * 256 + threadIdx.x;  // N*8
  if (tid >= N_NODES * 8) return;
  int i = tid >> 3, jq = (tid & 7) << 2;
  float s = dinv[i]; s *= s;
  float4 v = *(const float4*)(xw + (size_t)i * 32 + jq);
  float4 b = *(const float4*)(b0 + jq);
  *(float4*)(h + (size_t)i * 32 + jq) =
      make_float4(v.x * s + b.x, v.y * s + b.y, v.z * s + b.z, v.w * s + b.w);
}

// gather: h[i] += dinv1[i] * sum_p xw[ssrc[p]] * dinv1[ssrc[p]]
__global__ void k_conv1g(const int* __restrict__ off, const int* __restrict__ ssrc,
                         const float* __restrict__ xw, const float* __restrict__ dinv1,
                         float* __restrict__ h) {
  int tid = blockIdx.x * 256 + threadIdx.x;  // N*8
  if (tid >= N_NODES * 8) return;
  int i = tid >> 3, q = (tid & 7) << 2;
  int p0 = off[i], p1 = off[i + 1];
  float4 acc = make_float4(0.f, 0.f, 0.f, 0.f);
  for (int p = p0; p < p1; ++p) {
    int r = ssrc[p];
    float dr = dinv1[r];
    float4 v = *(const float4*)(xw + (size_t)r * 32 + q);
    acc.x += v.x * dr; acc.y += v.y * dr; acc.z += v.z * dr; acc.w += v.w * dr;
  }
  float di = dinv1[i];
  float* dst = h + (size_t)i * 32 + q;
  float4 cur = *(float4*)dst;
  cur.x += acc.x * di; cur.y += acc.y * di; cur.z += acc.z * di; cur.w += acc.w * di;
  *(float4*)dst = cur;
}

// ---------------- attention collapse ----------------
__global__ void k_prep_u(const float* __restrict__ Wnb, const float* __restrict__ bnb,
                         const float* __restrict__ Wself, const float* __restrict__ bself,
                         const float* __restrict__ Watt, const float* __restrict__ batt,
                         float* __restrict__ u) {
  int t = threadIdx.x;  // 64 threads
  if (t < 32) {
    float a = 0.f;
    for (int j = 0; j < 8; ++j) a += Wnb[t * 8 + j] * Watt[j];
    u[t] = a;
  } else {
    int k = t - 32;
    float a = 0.f;
    for (int j = 0; j < 8; ++j) a += Wself[k * 8 + j] * Watt[8 + j];
    u[32 + k] = a;
  }
  if (t == 0) {
    float a = batt[0];
    for (int j = 0; j < 8; ++j) a += bnb[j] * Watt[j];
    u[64] = a;
  }
  if (t == 1) {
    float a = 0.f;
    for (int j = 0; j < 8; ++j) a += bself[j] * Watt[8 + j];
    u[65] = a;
  }
}

// per-node: s1, s2 scalars + hw = h @ W1 (no bias)
__global__ __launch_bounds__(256) void k_node(const float* __restrict__ h,
                                              const float* __restrict__ u,
                                              const float* __restrict__ W1,
                                              float* __restrict__ s1, float* __restrict__ s2,
                                              float* __restrict__ hw) {
  __shared__ float w1s[256];
  __shared__ float us[66];
  int t = threadIdx.x;
  w1s[t] = W1[t];
  if (t < 66) us[t] = u[t];
  __syncthreads();
  int i = blockIdx.x * 256 + t;
  if (i >= N_NODES) return;
  float hv[32];
#pragma unroll
  for (int q = 0; q < 8; ++q)
    *(float4*)&hv[q * 4] = *(const float4*)(h + (size_t)i * 32 + q * 4);
  float a1 = us[64], a2 = us[65];
#pragma unroll
  for (int k = 0; k < 32; ++k) { a1 += hv[k] * us[k]; a2 += hv[k] * us[32 + k]; }
  s1[i] = a1; s2[i] = a2;
  float o[8] = {0.f, 0.f, 0.f, 0.f, 0.f, 0.f, 0.f, 0.f};
#pragma unroll
  for (int k = 0; k < 32; ++k) {
    float hk = hv[k];
#pragma unroll
    for (int j = 0; j < 8; ++j) o[j] += hk * w1s[k * 8 + j];
  }
  *(float4*)(hw + (size_t)i * 8) = make_float4(o[0], o[1], o[2], o[3]);
  *(float4*)(hw + (size_t)i * 8 + 4) = make_float4(o[4], o[5], o[6], o[7]);
}

// deg2 gather + dinv2, gate recomputed on the fly
__global__ void k_deg2g(const int* __restrict__ off, const int* __restrict__ ssrc,
                        const float* __restrict__ s1, const float* __restrict__ s2,
                        float* __restrict__ dinv2) {
  int i = blockIdx.x * 256 + threadIdx.x;
  if (i >= N_NODES) return;
  float s2i = s2[i];
  float sum = 0.f;
  int p1 = off[i + 1];
  for (int p = off[i]; p < p1; ++p) {
    int r = ssrc[p];
    float w = fmaxf(s1[r] + s2i, 0.f);
    float m = fminf(1.01f / (1.f + __expf(-w)), 1.f);
    sum += m * w;
  }
  dinv2[i] = rsqrtf(sum + 1.0f);
}

// out[i][:] = hw[i][:] * dinv2[i]^2 + b1
__global__ void k_oinit(const float* __restrict__ hw, const float* __restrict__ dinv2,
                        const float* __restrict__ b1, float* __restrict__ out) {
  int tid = blockIdx.x * 256 + threadIdx.x;  // N*2
  if (tid >= N_NODES * 2) return;
  int i = tid >> 1, jq = (tid & 1) << 2;
  float s = dinv2[i]; s *= s;
  float4 v = *(const float4*)(hw + (size_t)i * 8 + jq);
  float4 b = *(const float4*)(b1 + jq);
  *(float4*)(out + (size_t)i * 8 + jq) =
      make_float4(v.x * s + b.x, v.y * s + b.y, v.z * s + b.z, v.w * s + b.w);
}

// conv2 gather: out[i] += dinv2[i] * sum_p hw[r] * (gate(r,i) * dinv2[r])
__global__ void k_conv2g(const int* __restrict__ off, const int* __restrict__ ssrc,
                         const float* __restrict__ hw, const float* __restrict__ s1,
                         const float* __restrict__ s2, const float* __restrict__ dinv2,
                         float* __restrict__ out) {
  int tid = blockIdx.x * 256 + threadIdx.x;  // N*2
  if (tid >= N_NODES * 2) return;
  int i = tid >> 1, q = (tid & 1) << 2;
  float s2i = s2[i];
  float4 acc = make_float4(0.f, 0.f, 0.f, 0.f);
  int p1 = off[i + 1];
  for (int p = off[i]; p < p1; ++p) {
    int r = ssrc[p];
    float w = fmaxf(s1[r] + s2i, 0.f);
    float m = fminf(1.01f / (1.f + __expf(-w)), 1.f);
    float v = m * w * dinv2[r];
    float4 hv = *(const float4*)(hw + (size_t)r * 8 + q);
    acc.x += hv.x * v; acc.y += hv.y * v; acc.z += hv.z * v; acc.w += hv.w * v;
  }
  float di = dinv2[i];
  float* dst = out + (size_t)i * 8 + q;
  float4 cur = *(float4*)dst;
  cur.x += acc.x * di; cur.y += acc.y * di; cur.z += acc.z * di; cur.w += acc.w * di;
  *(float4*)dst = cur;
}

extern "C" void kernel_launch(void* const* d_in, const int* in_sizes, int n_in,
                              void* d_out, int out_size, void* d_ws, size_t ws_size,
                              hipStream_t stream) {
  const float* x     = (const float*)d_in[0];
  const int*   eidx  = (const int*)d_in[1];
  const int*   row   = eidx;
  const int*   col   = eidx + N_EDGES;
  const float* W0    = (const float*)d_in[2];
  const float* b0    = (const float*)d_in[3];
  const float* W1    = (const float*)d_in[4];
  const float* b1    = (const float*)d_in[5];
  const float* Wnb   = (const float*)d_in[6];
  const float* bnb   = (const float*)d_in[7];
  const float* Wself = (const float*)d_in[8];
  const float* bself = (const float*)d_in[9];
  const float* Watt  = (const float*)d_in[10];
  const float* batt  = (const float*)d_in[11];
  float* wsf = (float*)d_ws;

  // workspace layout (4-byte units), total ~8.51e6 (~34 MB):
  float* xw     = wsf + 0;          // N*32 (dead after k_conv1g, then reused)
  float* h      = wsf + 3200000;    // N*32
  int*   ssrc   = (int*)(wsf + 6400000);  // E
  int*   cnt    = (int*)(wsf + 8000000);  // N
  int*   off    = (int*)(wsf + 8100000);  // N+1
  int*   cursor = (int*)(wsf + 8200064);  // N
  float* dinv1  = wsf + 8300064;    // N
  float* dinv2  = wsf + 8400064;    // N
  int*   bsum   = (int*)(wsf + 8500064);  // 391
  int*   bpre   = (int*)(wsf + 8500560);  // 391
  float* u      = wsf + 8501056;    // 66
  // aliases into dead xw region (valid once conv1 is done):
  float* hw = wsf + 0;       // N*8
  float* s1 = wsf + 800000;  // N
  float* s2 = wsf + 900000;  // N

  float* out = (float*)d_out;

  k_zero_cnt<<<(N_NODES + 255) / 256, 256, 0, stream>>>(cnt, N_NODES);
  k_gemm_xw<<<(N_NODES + 127) / 128, 256, 0, stream>>>(x, W0, xw);
  k_count<<<(N_EDGES + 255) / 256, 256, 0, stream>>>(col, cnt, N_EDGES);
  k_scan1<<<SCAN_NB, 256, 0, stream>>>(cnt, off, bsum);
  k_scan2<<<1, 512, 0, stream>>>(bsum, bpre);
  k_scan3<<<(N_NODES + 255) / 256, 256, 0, stream>>>(cnt, bpre, off, cursor, dinv1);
  k_scatter<<<(N_EDGES + 255) / 256, 256, 0, stream>>>(row, col, cursor, ssrc);
  k_hinit<<<(N_NODES * 8 + 255) / 256, 256, 0, stream>>>(xw, dinv1, b0, h);
  k_conv1g<<<(N_NODES * 8 + 255) / 256, 256, 0, stream>>>(off, ssrc, xw, dinv1, h);
  k_prep_u<<<1, 64, 0, stream>>>(Wnb, bnb, Wself, bself, Watt, batt, u);
  k_node<<<(N_NODES + 255) / 256, 256, 0, stream>>>(h, u, W1, s1, s2, hw);
  k_deg2g<<<(N_NODES + 255) / 256, 256, 0, stream>>>(off, ssrc, s1, s2, dinv2);
  k_oinit<<<(N_NODES * 2 + 255) / 256, 256, 0, stream>>>(hw, dinv2, b1, out);
  k_conv2g<<<(N_NODES * 2 + 255) / 256, 256, 0, stream>>>(off, ssrc, hw, s1, s2, dinv2, out);
}